// Round 8
// baseline (2989.173 us; speedup 1.0000x reference)
//
#include <hip/hip_runtime.h>
#include <math.h>

// DynamiSE: GCN + 2x RK4 neural ODE + combine/LN.
// R1: CSR gather, coef folded into matmul (hs = dinv * x@W).
// R2: mm32 fused into agg epilogue, hs double-buffered.
// R3: merged pos/neg dispatch.
// R4: fp16 hs (64B gather rows). FAILED replay (read-before-write of poison).
// R5: blanket memset(0) of used ws every call (determinism insurance; keep!).
// R6: radix CSR build REGRESSED (bucket windows thrash all 8 L2s) -> reverted.
// R7: persistent ODE kernel: all 40 RK4 stages in ONE launch; x fp32 + ksum
//     fp16 live in LDS (block-owned nodes); only hs crosses blocks, synced by
//     a 2-level grid barrier. Residency guaranteed: 512 blocks x 512 thr =
//     exactly 2 blocks/CU (LDS 80.9KB/block, launch_bounds caps VGPR).

#define TPB 256
#define SCAN_T 1024

#define PB 512      // persistent block threads
#define PNB 392     // nodes per persistent block
#define PGH 256     // persistent blocks per graph
#define PG 512      // total persistent blocks

typedef _Float16 h8 __attribute__((ext_vector_type(8)));
typedef _Float16 h2v __attribute__((ext_vector_type(2)));
typedef float f8 __attribute__((ext_vector_type(8)));

// ---------- CSR build (R5-proven) ----------

struct SegG { const int* src; const int* dst; int n; int goff; };
struct FSeg { const int* src; const int* dst; int n; const int* offs; int* cur; };

__global__ void count4(SegG s0, SegG s1, SegG s2, SegG s3, int* __restrict__ cnt3) {
    int i = blockIdx.x * blockDim.x + threadIdx.x;
    SegG s; int e;
    if (i < s0.n) { s = s0; e = i; }
    else if (i < s0.n + s1.n) { s = s1; e = i - s0.n; }
    else if (i < s0.n + s1.n + s2.n) { s = s2; e = i - s0.n - s1.n; }
    else if (i < s0.n + s1.n + s2.n + s3.n) { s = s3; e = i - s0.n - s1.n - s2.n; }
    else return;
    atomicAdd(&cnt3[s.goff + s.dst[e]], 1);
}

__global__ void fill4(FSeg s0, FSeg s1, FSeg s2, FSeg s3, int* __restrict__ csr) {
    int i = blockIdx.x * blockDim.x + threadIdx.x;
    FSeg s; int e;
    if (i < s0.n) { s = s0; e = i; }
    else if (i < s0.n + s1.n) { s = s1; e = i - s0.n; }
    else if (i < s0.n + s1.n + s2.n) { s = s2; e = i - s0.n - s1.n; }
    else if (i < s0.n + s1.n + s2.n + s3.n) { s = s3; e = i - s0.n - s1.n - s2.n; }
    else return;
    int d = s.dst[e];
    int pos = s.offs[d] + atomicAdd(&s.cur[d], 1);
    csr[pos] = s.src[e];
}

__global__ void dinv_from_cnt(const int* __restrict__ cnt, float* __restrict__ dinv, int n) {
    int i = blockIdx.x * blockDim.x + threadIdx.x;
    if (i < n) dinv[i] = rsqrtf(1.0f + (float)cnt[i]);
}

__global__ void scan_block(const int* __restrict__ in, int n, int* __restrict__ out,
                           int* __restrict__ bsums) {
    __shared__ int sh[SCAN_T];
    int tx = threadIdx.x;
    int g = blockIdx.x * SCAN_T + tx;
    int v = (g < n) ? in[g] : 0;
    sh[tx] = v;
    __syncthreads();
    for (int off = 1; off < SCAN_T; off <<= 1) {
        int t = (tx >= off) ? sh[tx - off] : 0;
        __syncthreads();
        sh[tx] += t;
        __syncthreads();
    }
    if (g < n) out[g] = sh[tx] - v;
    if (tx == SCAN_T - 1) bsums[blockIdx.x] = sh[tx];
}

__global__ void scan_sums(int* __restrict__ bsums, int nb) {
    __shared__ int sh[SCAN_T];
    int tx = threadIdx.x;
    int v = (tx < nb) ? bsums[tx] : 0;
    sh[tx] = v;
    __syncthreads();
    for (int off = 1; off < SCAN_T; off <<= 1) {
        int t = (tx >= off) ? sh[tx - off] : 0;
        __syncthreads();
        sh[tx] += t;
        __syncthreads();
    }
    if (tx < nb) bsums[tx] = sh[tx] - v;
}

__global__ void scan_add(int* __restrict__ offs, const int* __restrict__ bsums, int n, int total) {
    int g = blockIdx.x * blockDim.x + threadIdx.x;
    if (g < n) offs[g] += bsums[g >> 10];
    if (g == 0) offs[n] = total;
}

// ---------- seed matmuls: hs16 = fp16(dinv * (x @ W)) ----------

__global__ void mm32_kernel(const float* __restrict__ x, const float* __restrict__ W,
                            const float* __restrict__ dinv, _Float16* __restrict__ hs, int N) {
    __shared__ float Ws[32][32];
    __shared__ float xs[8][32];
    int tid = threadIdx.x;
    for (int i = tid; i < 32 * 32; i += TPB) Ws[i >> 5][i & 31] = W[i];
    int base = blockIdx.x * 8;
    {
        int idx = base * 32 + tid;
        xs[tid >> 5][tid & 31] = (idx < N * 32) ? x[idx] : 0.0f;
    }
    __syncthreads();
    int row = tid >> 5, c = tid & 31;
    int gr = base + row;
    float acc = 0.0f;
#pragma unroll
    for (int k = 0; k < 32; ++k) acc += xs[row][k] * Ws[k][c];
    if (gr < N) hs[gr * 32 + c] = (_Float16)(acc * dinv[gr]);
}

__global__ void mm128_kernel(const float* __restrict__ x, const float* __restrict__ W,
                             const float* __restrict__ dinv, _Float16* __restrict__ hs, int N) {
    __shared__ float Ws[128][32];
    __shared__ float xs[8][128];
    int tid = threadIdx.x;
    for (int i = tid; i < 128 * 32; i += TPB) Ws[i >> 5][i & 31] = W[i];
    int base = blockIdx.x * 8;
    for (int i = tid; i < 8 * 128; i += TPB) {
        int idx = base * 128 + i;
        xs[i >> 7][i & 127] = (idx < N * 128) ? x[idx] : 0.0f;
    }
    __syncthreads();
    int row = tid >> 5, c = tid & 31;
    int gr = base + row;
    float acc = 0.0f;
#pragma unroll
    for (int k = 0; k < 128; ++k) acc += xs[row][k] * Ws[k][c];
    if (gr < N) hs[gr * 32 + c] = (_Float16)(acc * dinv[gr]);
}

// ---------- fused agg + RK4 stage (init stage-0 + fallback loop) ----------

struct Job {
    const int* offs; const int* csr;
    const _Float16* hs_in; _Float16* hs_out;
    const float* dinv; const float* dinv_next;
    const float* bias; const float* wt;
    float* ksum; float* x;
    const float* W;
};

__global__ __launch_bounds__(TPB) void agg_stage(Job jp, Job jn, int nbp, float t,
                                                 int stage, int do_mm, float* __restrict__ x2,
                                                 int N) {
    __shared__ float Ws[32][32];
    __shared__ float xts[64][36];
    __shared__ int soffs[65];

    bool isP = blockIdx.x < nbp;
    const Job& J = isP ? jp : jn;
    int bid = isP ? blockIdx.x : (blockIdx.x - nbp);
    int nbase = bid * 64;
    int tid = threadIdx.x;
    int lnode = tid >> 2, q = tid & 3;
    int node = nbase + lnode;
    bool valid = node < N;

    if (do_mm) {
        for (int i = tid; i < 32 * 32; i += TPB) Ws[i >> 5][i & 31] = J.W[i];
    }
    if (tid < 65) {
        int ix = nbase + tid; if (ix > N) ix = N;
        soffs[tid] = J.offs[ix];
    }
    __syncthreads();

    f8 xrow;
#pragma unroll
    for (int j = 0; j < 8; ++j) xrow[j] = 0.f;

    if (valid) {
        const h8* hsv = (const h8*)J.hs_in;
        const int* __restrict__ csr = J.csr;
        int r0 = soffs[lnode], r1 = soffs[lnode + 1];
        f8 acc = __builtin_convertvector(hsv[node * 4 + q], f8);
        int i = r0;
        for (; i + 4 <= r1; i += 4) {
            int s0 = csr[i], s1 = csr[i + 1], s2 = csr[i + 2], s3 = csr[i + 3];
            h8 v0 = hsv[s0 * 4 + q];
            h8 v1 = hsv[s1 * 4 + q];
            h8 v2 = hsv[s2 * 4 + q];
            h8 v3 = hsv[s3 * 4 + q];
            acc += (__builtin_convertvector(v0, f8) + __builtin_convertvector(v1, f8))
                 + (__builtin_convertvector(v2, f8) + __builtin_convertvector(v3, f8));
        }
        for (; i < r1; ++i)
            acc += __builtin_convertvector(hsv[csr[i] * 4 + q], f8);

        float dv = J.dinv[node];
        f8 bb = ((const f8*)J.bias)[q];
        f8 kv;
#pragma unroll
        for (int j = 0; j < 8; ++j) kv[j] = fmaxf(acc[j] * dv + bb[j], 0.f);
        if (J.wt) {
            f8 w = ((const f8*)J.wt)[q];
#pragma unroll
            for (int j = 0; j < 8; ++j) kv[j] *= 1.f / (1.f + expf(-t * w[j]));
        }
        int idx = node * 4 + q;
        f8* x8 = (f8*)J.x;
        f8* ks8 = (f8*)J.ksum;
        if (stage == 0) {
            x8[idx] = kv;
            ((f8*)x2)[idx] = kv;
            xrow = kv;
        } else if (stage == 4) {
            f8 ks = ks8[idx];
            f8 xv = x8[idx];
            const float cc = 0.1f / 6.0f;
#pragma unroll
            for (int j = 0; j < 8; ++j) xv[j] += cc * (ks[j] + kv[j]);
            x8[idx] = xv;
            xrow = xv;
        } else {
            float a = (stage == 3) ? 0.1f : 0.05f;
            f8 xv = x8[idx];
#pragma unroll
            for (int j = 0; j < 8; ++j) xrow[j] = xv[j] + a * kv[j];
            if (stage == 1) {
                ks8[idx] = kv;
            } else {
                f8 ks = ks8[idx];
#pragma unroll
                for (int j = 0; j < 8; ++j) ks[j] += 2.f * kv[j];
                ks8[idx] = ks;
            }
        }
    }

    if (do_mm) {
        if (valid) {
#pragma unroll
            for (int j = 0; j < 8; ++j) xts[lnode][q * 8 + j] = xrow[j];
        }
        __syncthreads();
        if (valid) {
            f8 accm;
#pragma unroll
            for (int j = 0; j < 8; ++j) accm[j] = 0.f;
#pragma unroll
            for (int k = 0; k < 32; ++k) {
                float xv = xts[lnode][k];
                f8 w = *(const f8*)&Ws[k][q * 8];
                accm += xv * w;
            }
            accm *= J.dinv_next[node];
            ((h8*)J.hs_out)[node * 4 + q] = __builtin_convertvector(accm, h8);
        }
    }
}

// ---------- persistent ODE kernel: 40 RK4 stages, x/ksum in LDS ----------
// 512 blocks x 512 threads = exactly 2 blocks/CU on 256 CUs (all resident).
// Grid barrier: 64 leaves x 8 blocks, monotonic counters (zeroed ws).
__global__ __launch_bounds__(PB, 4) void ode_persistent(
    const int* __restrict__ offs3, const int* __restrict__ csr3,
    const float* __restrict__ dinv3,
    _Float16* __restrict__ hp0, _Float16* __restrict__ hp1,
    _Float16* __restrict__ hn0, _Float16* __restrict__ hn1,
    const float* __restrict__ bp, const float* __restrict__ wtp, const float* __restrict__ Wp,
    const float* __restrict__ bn, const float* __restrict__ wtn, const float* __restrict__ Wn,
    float* __restrict__ x_pos, float* __restrict__ x_neg,
    int* __restrict__ bar_leaf, int* __restrict__ bar_root, int N)
{
    __shared__ float xs[PNB][33];   // 51,744 B (pad 33: conflict-free b32)
    __shared__ h2v  ks[PNB][16];    // 25,088 B (fp16 ksum)
    __shared__ float Wsh[32][32];   //  4,096 B  -> total 80,928 <= 81,920

    int tid = threadIdx.x;
    bool isP = blockIdx.x < PGH;
    int bid = isP ? blockIdx.x : (blockIdx.x - PGH);
    int nbase = bid * PNB;
    const int* offs = offs3 + (isP ? N : 2 * N);
    const float* dinv = dinv3 + (isP ? (size_t)N : (size_t)2 * N);
    const float* Wg = isP ? Wp : Wn;
    const float* bg = isP ? bp : bn;
    const float* wtg = isP ? wtp : wtn;
    _Float16* buf0 = isP ? hp0 : hn0;
    _Float16* buf1 = isP ? hp1 : hn1;
    float* xg = isP ? x_pos : x_neg;

    for (int i = tid; i < 32 * 32; i += PB) Wsh[i >> 5][i & 31] = Wg[i];

    int lnode = tid >> 2, q = tid & 3; // 128 nodes per chunk, 4 lanes/node
    f8 bb = ((const f8*)bg)[q];
    f8 wv = ((const f8*)wtg)[q];

    // load x (H0) into LDS
    for (int c = 0; c < 4; ++c) {
        int ln = c * 128 + lnode;
        int node = nbase + ln;
        if (ln < PNB && node < N) {
            f8 xv = ((const f8*)xg)[node * 4 + q];
#pragma unroll
            for (int j = 0; j < 8; ++j) xs[ln][q * 8 + j] = xv[j];
        }
    }
    __syncthreads();

    for (int cc = 0; cc < 40; ++cc) {
        int step = cc >> 2;
        int st = (cc & 3) + 1; // 1..4
        float t = 0.1f * (float)step + ((st == 1) ? 0.f : (st == 4) ? 0.1f : 0.05f);
        const _Float16* hin = (cc & 1) ? buf1 : buf0;
        _Float16* hout = (cc & 1) ? buf0 : buf1;
        bool do_mm = (cc != 39);

        f8 gate;
#pragma unroll
        for (int j = 0; j < 8; ++j) gate[j] = 1.f / (1.f + expf(-t * wv[j]));

        for (int c = 0; c < 4; ++c) {
            int ln = c * 128 + lnode;
            int node = nbase + ln;
            bool v = (ln < PNB) && (node < N);
            if (!v) continue;

            const h8* hsv = (const h8*)hin;
            int r0 = offs[node], r1 = offs[node + 1];
            f8 acc = __builtin_convertvector(hsv[node * 4 + q], f8); // self
            int i = r0;
            for (; i + 4 <= r1; i += 4) {
                int s0 = csr3[i], s1 = csr3[i + 1], s2 = csr3[i + 2], s3 = csr3[i + 3];
                h8 v0 = hsv[s0 * 4 + q];
                h8 v1 = hsv[s1 * 4 + q];
                h8 v2 = hsv[s2 * 4 + q];
                h8 v3 = hsv[s3 * 4 + q];
                acc += (__builtin_convertvector(v0, f8) + __builtin_convertvector(v1, f8))
                     + (__builtin_convertvector(v2, f8) + __builtin_convertvector(v3, f8));
            }
            for (; i < r1; ++i)
                acc += __builtin_convertvector(hsv[csr3[i] * 4 + q], f8);

            float dv = dinv[node];
            f8 kv;
#pragma unroll
            for (int j = 0; j < 8; ++j)
                kv[j] = fmaxf(acc[j] * dv + bb[j], 0.f) * gate[j];

            // x/ksum update (LDS)
            f8 xv;
#pragma unroll
            for (int j = 0; j < 8; ++j) xv[j] = xs[ln][q * 8 + j];
            f8 xrow;
            if (st == 4) {
                const float hc = 0.1f / 6.0f;
#pragma unroll
                for (int jj = 0; jj < 4; ++jj) {
                    h2v kk = ks[ln][q * 4 + jj];
                    xrow[2 * jj] = xv[2 * jj] + hc * ((float)kk[0] + kv[2 * jj]);
                    xrow[2 * jj + 1] = xv[2 * jj + 1] + hc * ((float)kk[1] + kv[2 * jj + 1]);
                }
#pragma unroll
                for (int j = 0; j < 8; ++j) xs[ln][q * 8 + j] = xrow[j];
            } else {
                float a = (st == 3) ? 0.1f : 0.05f;
#pragma unroll
                for (int j = 0; j < 8; ++j) xrow[j] = xv[j] + a * kv[j];
                if (st == 1) {
#pragma unroll
                    for (int jj = 0; jj < 4; ++jj) {
                        h2v kk;
                        kk[0] = (_Float16)kv[2 * jj];
                        kk[1] = (_Float16)kv[2 * jj + 1];
                        ks[ln][q * 4 + jj] = kk;
                    }
                } else {
#pragma unroll
                    for (int jj = 0; jj < 4; ++jj) {
                        h2v kk = ks[ln][q * 4 + jj];
                        kk[0] = (_Float16)((float)kk[0] + 2.f * kv[2 * jj]);
                        kk[1] = (_Float16)((float)kk[1] + 2.f * kv[2 * jj + 1]);
                        ks[ln][q * 4 + jj] = kk;
                    }
                }
            }

            if (do_mm) {
                // quad all-gather of xrow via shfl (quad-uniform active)
                float lo16[16];
#pragma unroll
                for (int j = 0; j < 8; ++j) {
                    float o = __shfl_xor(xrow[j], 1, 64);
                    lo16[j] = (q & 1) ? o : xrow[j];
                    lo16[8 + j] = (q & 1) ? xrow[j] : o;
                }
                int base1 = (q & ~1) * 8;
                int base2 = ((q ^ 2) & ~1) * 8;
                f8 accm;
#pragma unroll
                for (int j = 0; j < 8; ++j) accm[j] = 0.f;
#pragma unroll
                for (int k = 0; k < 16; ++k)
                    accm += lo16[k] * ((const f8*)&Wsh[base1 + k][0])[q];
#pragma unroll
                for (int k = 0; k < 16; ++k) {
                    float o2 = __shfl_xor(lo16[k], 2, 64);
                    accm += o2 * ((const f8*)&Wsh[base2 + k][0])[q];
                }
                accm *= dv;
                ((h8*)hout)[node * 4 + q] = __builtin_convertvector(accm, h8);
            }
        }

        // grid barrier (skip after last stage)
        if (cc != 39) {
            __syncthreads();
            if (tid == 0) {
                __threadfence();
                int leaf = blockIdx.x >> 3;
                int old = atomicAdd(&bar_leaf[leaf], 1);
                if ((old & 7) == 7) atomicAdd(bar_root, 1);
                int target = 64 * (cc + 1);
                while (__hip_atomic_load(bar_root, __ATOMIC_RELAXED,
                                         __HIP_MEMORY_SCOPE_AGENT) < target)
                    __builtin_amdgcn_s_sleep(8);
                __threadfence();
            }
            __syncthreads();
        }
    }

    // write back x
    for (int c = 0; c < 4; ++c) {
        int ln = c * 128 + lnode;
        int node = nbase + ln;
        if (ln < PNB && node < N) {
            f8 out;
#pragma unroll
            for (int j = 0; j < 8; ++j) out[j] = xs[ln][q * 8 + j];
            ((f8*)xg)[node * 4 + q] = out;
        }
    }
}

// ---------- combine + layernorm ----------

__global__ void combine_kernel(const float* __restrict__ zp, const float* __restrict__ zn,
                               const float* __restrict__ Wc, const float* __restrict__ bc,
                               const float* __restrict__ g, const float* __restrict__ be,
                               float* __restrict__ out, int N) {
    __shared__ float Ws[64][32];
    __shared__ float zs[8][64];
    int tid = threadIdx.x;
    for (int i = tid; i < 64 * 32; i += TPB) Ws[i >> 5][i & 31] = Wc[i];
    int base = blockIdx.x * 8;
    {
        int r = tid >> 5, c = tid & 31;
        int gr = base + r;
        zs[r][c] = (gr < N) ? zp[gr * 32 + c] : 0.0f;
        zs[r][32 + c] = (gr < N) ? zn[gr * 32 + c] : 0.0f;
    }
    __syncthreads();
    int row = tid >> 5, c = tid & 31;
    int gr = base + row;
    float acc = bc[c];
#pragma unroll
    for (int k = 0; k < 64; ++k) acc += zs[row][k] * Ws[k][c];
    float s = acc, sq = acc * acc;
#pragma unroll
    for (int off = 16; off; off >>= 1) {
        s += __shfl_xor(s, off, 32);
        sq += __shfl_xor(sq, off, 32);
    }
    float mu = s * (1.0f / 32.0f);
    float var = sq * (1.0f / 32.0f) - mu * mu;
    float y = (acc - mu) * rsqrtf(var + 1e-5f) * g[c] + be[c];
    if (gr < N) out[gr * 32 + c] = y;
}

// ---------- host orchestration ----------

extern "C" void kernel_launch(void* const* d_in, const int* in_sizes, int n_in,
                              void* d_out, int out_size, void* d_ws, size_t ws_size,
                              hipStream_t stream) {
    const float* H_t = (const float*)d_in[0];
    const int* Apos = (const int*)d_in[1];
    const int* Aneg = (const int*)d_in[2];
    const int* dApos = (const int*)d_in[3];
    const int* dAneg = (const int*)d_in[4];
    const float* W_init = (const float*)d_in[5];
    const float* b_init = (const float*)d_in[6];
    const float* W_pos = (const float*)d_in[7];
    const float* b_pos = (const float*)d_in[8];
    const float* wt_pos = (const float*)d_in[9];
    const float* W_neg = (const float*)d_in[10];
    const float* b_neg = (const float*)d_in[11];
    const float* wt_neg = (const float*)d_in[12];
    const float* W_comb = (const float*)d_in[13];
    const float* b_comb = (const float*)d_in[14];
    const float* ln_g = (const float*)d_in[15];
    const float* ln_b = (const float*)d_in[16];

    const int N = in_sizes[0] / 128;
    const int E1 = in_sizes[1] / 2;
    const int E2 = in_sizes[2] / 2;
    const int DE1 = in_sizes[3] / 2;
    const int DE2 = in_sizes[4] / 2;
    const int Etot = E1 + E2 + DE1 + DE2;

    const int* Apos_src = Apos, * Apos_dst = Apos + E1;
    const int* Aneg_src = Aneg, * Aneg_dst = Aneg + E2;
    const int* dApos_src = dApos, * dApos_dst = dApos + DE1;
    const int* dAneg_src = dAneg, * dAneg_dst = dAneg + DE2;

    const size_t n32 = (size_t)N * 32;
    const size_t szf = n32 * 4;
    const size_t szh = n32 * 2;
    auto al = [](size_t b) { return (b + 255) & ~(size_t)255; };

    size_t small_bytes = 3 * al((size_t)(3 * N) * 4)
                       + al((3 * (size_t)N + 1) * 4)
                       + al((size_t)Etot * 4)
                       + al(SCAN_T * 4) + al(65 * 4);
    size_t need_merged = 4 * al(szf) + 4 * al(szh) + small_bytes;
    bool merged = ws_size >= need_merged + 4096;
    bool persistent = merged && (N <= PNB * PGH);

    char* p = (char*)d_ws;
    auto alloc = [&](size_t bytes) -> void* {
        void* r = (void*)p;
        p += al(bytes);
        return r;
    };
    float* x_pos = (float*)alloc(szf);
    float* x_neg = (float*)alloc(szf);
    float* ksum_p = (float*)alloc(szf);
    float* ksum_n = merged ? (float*)alloc(szf) : ksum_p;
    _Float16* hs_pa = (_Float16*)alloc(szh);
    _Float16* hs_pb = (_Float16*)alloc(szh);
    _Float16* hs_na = merged ? (_Float16*)alloc(szh) : hs_pa;
    _Float16* hs_nb = merged ? (_Float16*)alloc(szh) : hs_pb;
    float* dinv3 = (float*)alloc((size_t)(3 * N) * 4);
    int* cnt3 = (int*)alloc((size_t)(3 * N) * 4);
    int* cur3 = (int*)alloc((size_t)(3 * N) * 4);
    int* offs3 = (int*)alloc((3 * (size_t)N + 1) * 4);
    int* csr3 = (int*)alloc((size_t)Etot * 4);
    int* bsums = (int*)alloc(SCAN_T * 4);
    int* bar = (int*)alloc(65 * 4); // leaf[64] + root

    size_t used = (size_t)(p - (char*)d_ws);
    if (used > ws_size) used = ws_size;

    // R5: blanket zero of every used ws byte — deterministic initial state on
    // every call/replay (harness poisons ws with 0xAA). Also zeroes barrier.
    hipMemsetAsync(d_ws, 0, used, stream);

    float* dinv_all = dinv3, * dinv_pos = dinv3 + N, * dinv_neg = dinv3 + 2 * N;
    const int* offs_all = offs3, * offs_pos = offs3 + N, * offs_neg = offs3 + 2 * N;

    dim3 blk(TPB);
    auto gblk = [](int n) { return dim3((n + TPB - 1) / TPB); };
    dim3 grid_rows((N + 7) / 8);
    const int nb64 = (N + 63) / 64;
    const int n3 = 3 * N;
    const int nbs = (n3 + SCAN_T - 1) / SCAN_T;

    // ---- fused CSR build (R5 path) ----
    SegG s0 = { Apos_src, Apos_dst, E1, 0 };
    SegG s1 = { Aneg_src, Aneg_dst, E2, 0 };
    SegG s2 = { dApos_src, dApos_dst, DE1, N };
    SegG s3 = { dAneg_src, dAneg_dst, DE2, 2 * N };
    count4<<<gblk(Etot), blk, 0, stream>>>(s0, s1, s2, s3, cnt3);
    dinv_from_cnt<<<gblk(n3), blk, 0, stream>>>(cnt3, dinv3, n3);
    scan_block<<<nbs, SCAN_T, 0, stream>>>(cnt3, n3, offs3, bsums);
    scan_sums<<<1, SCAN_T, 0, stream>>>(bsums, nbs);
    scan_add<<<gblk(n3), blk, 0, stream>>>(offs3, bsums, n3, Etot);
    {
        FSeg f0 = { Apos_src, Apos_dst, E1, offs3, cur3 };
        FSeg f1 = { Aneg_src, Aneg_dst, E2, offs3, cur3 };
        FSeg f2 = { dApos_src, dApos_dst, DE1, offs3 + N, cur3 + N };
        FSeg f3 = { dAneg_src, dAneg_dst, DE2, offs3 + 2 * N, cur3 + 2 * N };
        fill4<<<gblk(Etot), blk, 0, stream>>>(f0, f1, f2, f3, csr3);
    }

    auto mkjob = [&](const int* offs, const _Float16* hs_in, _Float16* hs_out,
                     const float* dinv, const float* dinv_next, const float* bias,
                     const float* wt, float* ksum, float* x, const float* W) {
        Job j; j.offs = offs; j.csr = csr3; j.hs_in = hs_in; j.hs_out = hs_out;
        j.dinv = dinv; j.dinv_next = dinv_next; j.bias = bias; j.wt = wt;
        j.ksum = ksum; j.x = x; j.W = W; return j;
    };

    // ---- init GCN: H0 = relu(gcn(H_t)) -> x_pos, x_neg; epilogue seeds pos hs ----
    mm128_kernel<<<grid_rows, blk, 0, stream>>>(H_t, W_init, dinv_all, hs_pa, N);
    {
        Job j0 = mkjob(offs_all, hs_pa, hs_pb, dinv_all, dinv_pos, b_init,
                       nullptr, nullptr, x_pos, W_pos);
        agg_stage<<<nb64, blk, 0, stream>>>(j0, j0, nb64, 0.0f, 0, 1, x_neg, N);
    }
    // seed hs for neg ODE
    mm32_kernel<<<grid_rows, blk, 0, stream>>>(x_neg, W_neg, dinv_neg, hs_nb, N);

    if (persistent) {
        ode_persistent<<<PG, PB, 0, stream>>>(
            offs3, csr3, dinv3,
            hs_pb, hs_pa, hs_nb, hs_na,
            b_pos, wt_pos, W_pos, b_neg, wt_neg, W_neg,
            x_pos, x_neg, bar, bar + 64, N);
    } else if (merged) {
        for (int s = 0; s < 10; ++s) {
            float t0 = 0.1f * (float)s;
            int last_mm = (s == 9) ? 0 : 1;
            Job p1 = mkjob(offs_pos, hs_pb, hs_pa, dinv_pos, dinv_pos, b_pos, wt_pos, ksum_p, x_pos, W_pos);
            Job n1 = mkjob(offs_neg, hs_nb, hs_na, dinv_neg, dinv_neg, b_neg, wt_neg, ksum_n, x_neg, W_neg);
            agg_stage<<<2 * nb64, blk, 0, stream>>>(p1, n1, nb64, t0, 1, 1, nullptr, N);
            Job p2 = p1; p2.hs_in = hs_pa; p2.hs_out = hs_pb;
            Job n2 = n1; n2.hs_in = hs_na; n2.hs_out = hs_nb;
            agg_stage<<<2 * nb64, blk, 0, stream>>>(p2, n2, nb64, t0 + 0.05f, 2, 1, nullptr, N);
            agg_stage<<<2 * nb64, blk, 0, stream>>>(p1, n1, nb64, t0 + 0.05f, 3, 1, nullptr, N);
            agg_stage<<<2 * nb64, blk, 0, stream>>>(p2, n2, nb64, t0 + 0.1f, 4, last_mm, nullptr, N);
        }
    } else {
        for (int ode = 0; ode < 2; ++ode) {
            float* x = ode ? x_neg : x_pos;
            const float* W = ode ? W_neg : W_pos;
            const float* b = ode ? b_neg : b_pos;
            const float* wt = ode ? wt_neg : wt_pos;
            const float* dinv = ode ? dinv_neg : dinv_pos;
            const int* offs = ode ? offs_neg : offs_pos;
            if (ode == 1) {
                mm32_kernel<<<grid_rows, blk, 0, stream>>>(x, W, dinv, hs_pb, N);
            }
            for (int s = 0; s < 10; ++s) {
                float t0 = 0.1f * (float)s;
                int last_mm = (s == 9) ? 0 : 1;
                Job j1 = mkjob(offs, hs_pb, hs_pa, dinv, dinv, b, wt, ksum_p, x, W);
                Job j2 = j1; j2.hs_in = hs_pa; j2.hs_out = hs_pb;
                agg_stage<<<nb64, blk, 0, stream>>>(j1, j1, nb64, t0, 1, 1, nullptr, N);
                agg_stage<<<nb64, blk, 0, stream>>>(j2, j2, nb64, t0 + 0.05f, 2, 1, nullptr, N);
                agg_stage<<<nb64, blk, 0, stream>>>(j1, j1, nb64, t0 + 0.05f, 3, 1, nullptr, N);
                agg_stage<<<nb64, blk, 0, stream>>>(j2, j2, nb64, t0 + 0.1f, 4, last_mm, nullptr, N);
            }
        }
    }

    // ---- combine + layernorm ----
    combine_kernel<<<grid_rows, blk, 0, stream>>>(x_pos, x_neg, W_comb, b_comb, ln_g, ln_b,
                                                  (float*)d_out, N);
}

// Round 9
// 2144.139 us; speedup vs baseline: 1.3941x; 1.3941x over previous
//
#include <hip/hip_runtime.h>
#include <math.h>

// DynamiSE: GCN + 2x RK4 neural ODE + combine/LN.
// R1: CSR gather, coef folded into matmul (hs = dinv * x@W).
// R2: mm32 fused into agg epilogue, hs double-buffered.
// R3: merged pos/neg dispatch.
// R4: fp16 hs (64B gather rows). FAILED replay (read-before-write of poison).
// R5: blanket memset(0) of used ws every call (determinism insurance; keep!).
// R6: radix CSR build REGRESSED (bucket windows thrash all 8 L2s) -> reverted.
// R7: persistent kernel REGRESSED (FETCH 3.3GB: gather is fetch-throughput-
//     bound; persistent halves waves/CU + adds barriers) -> reverted.
// R9: R5 loop + XCD-split scheduling (blockIdx%8<4 -> pos, else neg: each
//     XCD's L2 caches ONE graph's hs, 6.4MB vs 12.8MB working set) + ksum in
//     fp16 (validated by R8's absmax: unchanged at 0.015625).

#define TPB 256
#define SCAN_T 1024

typedef _Float16 h8 __attribute__((ext_vector_type(8)));
typedef float f8 __attribute__((ext_vector_type(8)));

// ---------- CSR build (R5-proven) ----------

struct SegG { const int* src; const int* dst; int n; int goff; };
struct FSeg { const int* src; const int* dst; int n; const int* offs; int* cur; };

__global__ void count4(SegG s0, SegG s1, SegG s2, SegG s3, int* __restrict__ cnt3) {
    int i = blockIdx.x * blockDim.x + threadIdx.x;
    SegG s; int e;
    if (i < s0.n) { s = s0; e = i; }
    else if (i < s0.n + s1.n) { s = s1; e = i - s0.n; }
    else if (i < s0.n + s1.n + s2.n) { s = s2; e = i - s0.n - s1.n; }
    else if (i < s0.n + s1.n + s2.n + s3.n) { s = s3; e = i - s0.n - s1.n - s2.n; }
    else return;
    atomicAdd(&cnt3[s.goff + s.dst[e]], 1);
}

__global__ void fill4(FSeg s0, FSeg s1, FSeg s2, FSeg s3, int* __restrict__ csr) {
    int i = blockIdx.x * blockDim.x + threadIdx.x;
    FSeg s; int e;
    if (i < s0.n) { s = s0; e = i; }
    else if (i < s0.n + s1.n) { s = s1; e = i - s0.n; }
    else if (i < s0.n + s1.n + s2.n) { s = s2; e = i - s0.n - s1.n; }
    else if (i < s0.n + s1.n + s2.n + s3.n) { s = s3; e = i - s0.n - s1.n - s2.n; }
    else return;
    int d = s.dst[e];
    int pos = s.offs[d] + atomicAdd(&s.cur[d], 1);
    csr[pos] = s.src[e];
}

__global__ void dinv_from_cnt(const int* __restrict__ cnt, float* __restrict__ dinv, int n) {
    int i = blockIdx.x * blockDim.x + threadIdx.x;
    if (i < n) dinv[i] = rsqrtf(1.0f + (float)cnt[i]);
}

__global__ void scan_block(const int* __restrict__ in, int n, int* __restrict__ out,
                           int* __restrict__ bsums) {
    __shared__ int sh[SCAN_T];
    int tx = threadIdx.x;
    int g = blockIdx.x * SCAN_T + tx;
    int v = (g < n) ? in[g] : 0;
    sh[tx] = v;
    __syncthreads();
    for (int off = 1; off < SCAN_T; off <<= 1) {
        int t = (tx >= off) ? sh[tx - off] : 0;
        __syncthreads();
        sh[tx] += t;
        __syncthreads();
    }
    if (g < n) out[g] = sh[tx] - v;
    if (tx == SCAN_T - 1) bsums[blockIdx.x] = sh[tx];
}

__global__ void scan_sums(int* __restrict__ bsums, int nb) {
    __shared__ int sh[SCAN_T];
    int tx = threadIdx.x;
    int v = (tx < nb) ? bsums[tx] : 0;
    sh[tx] = v;
    __syncthreads();
    for (int off = 1; off < SCAN_T; off <<= 1) {
        int t = (tx >= off) ? sh[tx - off] : 0;
        __syncthreads();
        sh[tx] += t;
        __syncthreads();
    }
    if (tx < nb) bsums[tx] = sh[tx] - v;
}

__global__ void scan_add(int* __restrict__ offs, const int* __restrict__ bsums, int n, int total) {
    int g = blockIdx.x * blockDim.x + threadIdx.x;
    if (g < n) offs[g] += bsums[g >> 10];
    if (g == 0) offs[n] = total;
}

// ---------- seed matmuls: hs16 = fp16(dinv * (x @ W)) ----------

__global__ void mm32_kernel(const float* __restrict__ x, const float* __restrict__ W,
                            const float* __restrict__ dinv, _Float16* __restrict__ hs, int N) {
    __shared__ float Ws[32][32];
    __shared__ float xs[8][32];
    int tid = threadIdx.x;
    for (int i = tid; i < 32 * 32; i += TPB) Ws[i >> 5][i & 31] = W[i];
    int base = blockIdx.x * 8;
    {
        int idx = base * 32 + tid;
        xs[tid >> 5][tid & 31] = (idx < N * 32) ? x[idx] : 0.0f;
    }
    __syncthreads();
    int row = tid >> 5, c = tid & 31;
    int gr = base + row;
    float acc = 0.0f;
#pragma unroll
    for (int k = 0; k < 32; ++k) acc += xs[row][k] * Ws[k][c];
    if (gr < N) hs[gr * 32 + c] = (_Float16)(acc * dinv[gr]);
}

__global__ void mm128_kernel(const float* __restrict__ x, const float* __restrict__ W,
                             const float* __restrict__ dinv, _Float16* __restrict__ hs, int N) {
    __shared__ float Ws[128][32];
    __shared__ float xs[8][128];
    int tid = threadIdx.x;
    for (int i = tid; i < 128 * 32; i += TPB) Ws[i >> 5][i & 31] = W[i];
    int base = blockIdx.x * 8;
    for (int i = tid; i < 8 * 128; i += TPB) {
        int idx = base * 128 + i;
        xs[i >> 7][i & 127] = (idx < N * 128) ? x[idx] : 0.0f;
    }
    __syncthreads();
    int row = tid >> 5, c = tid & 31;
    int gr = base + row;
    float acc = 0.0f;
#pragma unroll
    for (int k = 0; k < 128; ++k) acc += xs[row][k] * Ws[k][c];
    if (gr < N) hs[gr * 32 + c] = (_Float16)(acc * dinv[gr]);
}

// ---------- fused CSR aggregate + RK4 stage + next matmul ----------

struct Job {
    const int* offs; const int* csr;
    const _Float16* hs_in; _Float16* hs_out;
    const float* dinv; const float* dinv_next;
    const float* bias; const float* wt;
    _Float16* ksum; float* x;
    const float* W;
};

// 4 lanes/node (8 channels each), 64 nodes/block.
// split=0: blocks [0,nbg) -> jp, rest -> jn (nbg = #blocks for jp).
// split=1: XCD-aware: blockIdx%8 < 4 -> jp else jn; bid = (blk>>3)*4 + (blk&3).
//          Each XCD's L2 then caches only ONE graph's hs working set.
__global__ __launch_bounds__(TPB) void agg_stage(Job jp, Job jn, int nbg, float t,
                                                 int stage, int do_mm, int split,
                                                 float* __restrict__ x2, int N) {
    __shared__ float Ws[32][32];
    __shared__ float xts[64][36];
    __shared__ int soffs[65];

    bool isP; int bid;
    if (split) {
        int xcd = blockIdx.x & 7;
        isP = xcd < 4;
        bid = ((int)blockIdx.x >> 3) * 4 + (xcd & 3);
        if (bid >= nbg) return; // whole block uniform -> safe before barriers
    } else {
        isP = (int)blockIdx.x < nbg;
        bid = isP ? blockIdx.x : (blockIdx.x - nbg);
    }
    const Job& J = isP ? jp : jn;
    int nbase = bid * 64;
    int tid = threadIdx.x;
    int lnode = tid >> 2, q = tid & 3;
    int node = nbase + lnode;
    bool valid = node < N;

    if (do_mm) {
        for (int i = tid; i < 32 * 32; i += TPB) Ws[i >> 5][i & 31] = J.W[i];
    }
    if (tid < 65) {
        int ix = nbase + tid; if (ix > N) ix = N;
        soffs[tid] = J.offs[ix];
    }
    __syncthreads();

    f8 xrow;
#pragma unroll
    for (int j = 0; j < 8; ++j) xrow[j] = 0.f;

    if (valid) {
        const h8* hsv = (const h8*)J.hs_in;
        const int* __restrict__ csr = J.csr;
        int r0 = soffs[lnode], r1 = soffs[lnode + 1];
        f8 acc = __builtin_convertvector(hsv[node * 4 + q], f8); // self-loop
        int i = r0;
        for (; i + 4 <= r1; i += 4) {
            int s0 = csr[i], s1 = csr[i + 1], s2 = csr[i + 2], s3 = csr[i + 3];
            h8 v0 = hsv[s0 * 4 + q];
            h8 v1 = hsv[s1 * 4 + q];
            h8 v2 = hsv[s2 * 4 + q];
            h8 v3 = hsv[s3 * 4 + q];
            acc += (__builtin_convertvector(v0, f8) + __builtin_convertvector(v1, f8))
                 + (__builtin_convertvector(v2, f8) + __builtin_convertvector(v3, f8));
        }
        for (; i < r1; ++i)
            acc += __builtin_convertvector(hsv[csr[i] * 4 + q], f8);

        float dv = J.dinv[node];
        f8 bb = ((const f8*)J.bias)[q];
        f8 kv;
#pragma unroll
        for (int j = 0; j < 8; ++j) kv[j] = fmaxf(acc[j] * dv + bb[j], 0.f);
        if (J.wt) {
            f8 w = ((const f8*)J.wt)[q];
#pragma unroll
            for (int j = 0; j < 8; ++j) kv[j] *= 1.f / (1.f + expf(-t * w[j]));
        }
        int idx = node * 4 + q;
        f8* x8 = (f8*)J.x;
        h8* ks8 = (h8*)J.ksum; // fp16 ksum (validated R8: absmax unchanged)
        if (stage == 0) {
            x8[idx] = kv;
            ((f8*)x2)[idx] = kv;
            xrow = kv;
        } else if (stage == 4) {
            f8 ks = __builtin_convertvector(ks8[idx], f8);
            f8 xv = x8[idx];
            const float cc = 0.1f / 6.0f;
#pragma unroll
            for (int j = 0; j < 8; ++j) xv[j] += cc * (ks[j] + kv[j]);
            x8[idx] = xv;
            xrow = xv;
        } else {
            float a = (stage == 3) ? 0.1f : 0.05f;
            f8 xv = x8[idx];
#pragma unroll
            for (int j = 0; j < 8; ++j) xrow[j] = xv[j] + a * kv[j];
            if (stage == 1) {
                ks8[idx] = __builtin_convertvector(kv, h8);
            } else {
                f8 ks = __builtin_convertvector(ks8[idx], f8);
#pragma unroll
                for (int j = 0; j < 8; ++j) ks[j] += 2.f * kv[j];
                ks8[idx] = __builtin_convertvector(ks, h8);
            }
        }
    }

    if (do_mm) {
        if (valid) {
#pragma unroll
            for (int j = 0; j < 8; ++j) xts[lnode][q * 8 + j] = xrow[j];
        }
        __syncthreads();
        if (valid) {
            f8 accm;
#pragma unroll
            for (int j = 0; j < 8; ++j) accm[j] = 0.f;
#pragma unroll
            for (int k = 0; k < 32; ++k) {
                float xv = xts[lnode][k];
                f8 w = *(const f8*)&Ws[k][q * 8];
                accm += xv * w;
            }
            accm *= J.dinv_next[node];
            ((h8*)J.hs_out)[node * 4 + q] = __builtin_convertvector(accm, h8);
        }
    }
}

// ---------- combine + layernorm ----------

__global__ void combine_kernel(const float* __restrict__ zp, const float* __restrict__ zn,
                               const float* __restrict__ Wc, const float* __restrict__ bc,
                               const float* __restrict__ g, const float* __restrict__ be,
                               float* __restrict__ out, int N) {
    __shared__ float Ws[64][32];
    __shared__ float zs[8][64];
    int tid = threadIdx.x;
    for (int i = tid; i < 64 * 32; i += TPB) Ws[i >> 5][i & 31] = Wc[i];
    int base = blockIdx.x * 8;
    {
        int r = tid >> 5, c = tid & 31;
        int gr = base + r;
        zs[r][c] = (gr < N) ? zp[gr * 32 + c] : 0.0f;
        zs[r][32 + c] = (gr < N) ? zn[gr * 32 + c] : 0.0f;
    }
    __syncthreads();
    int row = tid >> 5, c = tid & 31;
    int gr = base + row;
    float acc = bc[c];
#pragma unroll
    for (int k = 0; k < 64; ++k) acc += zs[row][k] * Ws[k][c];
    float s = acc, sq = acc * acc;
#pragma unroll
    for (int off = 16; off; off >>= 1) {
        s += __shfl_xor(s, off, 32);
        sq += __shfl_xor(sq, off, 32);
    }
    float mu = s * (1.0f / 32.0f);
    float var = sq * (1.0f / 32.0f) - mu * mu;
    float y = (acc - mu) * rsqrtf(var + 1e-5f) * g[c] + be[c];
    if (gr < N) out[gr * 32 + c] = y;
}

// ---------- host orchestration ----------

extern "C" void kernel_launch(void* const* d_in, const int* in_sizes, int n_in,
                              void* d_out, int out_size, void* d_ws, size_t ws_size,
                              hipStream_t stream) {
    const float* H_t = (const float*)d_in[0];
    const int* Apos = (const int*)d_in[1];
    const int* Aneg = (const int*)d_in[2];
    const int* dApos = (const int*)d_in[3];
    const int* dAneg = (const int*)d_in[4];
    const float* W_init = (const float*)d_in[5];
    const float* b_init = (const float*)d_in[6];
    const float* W_pos = (const float*)d_in[7];
    const float* b_pos = (const float*)d_in[8];
    const float* wt_pos = (const float*)d_in[9];
    const float* W_neg = (const float*)d_in[10];
    const float* b_neg = (const float*)d_in[11];
    const float* wt_neg = (const float*)d_in[12];
    const float* W_comb = (const float*)d_in[13];
    const float* b_comb = (const float*)d_in[14];
    const float* ln_g = (const float*)d_in[15];
    const float* ln_b = (const float*)d_in[16];

    const int N = in_sizes[0] / 128;
    const int E1 = in_sizes[1] / 2;
    const int E2 = in_sizes[2] / 2;
    const int DE1 = in_sizes[3] / 2;
    const int DE2 = in_sizes[4] / 2;
    const int Etot = E1 + E2 + DE1 + DE2;

    const int* Apos_src = Apos, * Apos_dst = Apos + E1;
    const int* Aneg_src = Aneg, * Aneg_dst = Aneg + E2;
    const int* dApos_src = dApos, * dApos_dst = dApos + DE1;
    const int* dAneg_src = dAneg, * dAneg_dst = dAneg + DE2;

    const size_t n32 = (size_t)N * 32;
    const size_t szf = n32 * 4;
    const size_t szh = n32 * 2;
    auto al = [](size_t b) { return (b + 255) & ~(size_t)255; };

    size_t small_bytes = 3 * al((size_t)(3 * N) * 4)   /* dinv3, cnt3, cur3 */
                       + al((3 * (size_t)N + 1) * 4)   /* offs3 */
                       + al((size_t)Etot * 4)          /* csr3 */
                       + al(SCAN_T * 4);
    // 2 fp32 x + 2 fp16 ksum + 4 fp16 hs
    size_t need_merged = 2 * al(szf) + 6 * al(szh) + small_bytes;
    bool merged = ws_size >= need_merged + 4096;

    char* p = (char*)d_ws;
    auto alloc = [&](size_t bytes) -> void* {
        void* r = (void*)p;
        p += al(bytes);
        return r;
    };
    float* x_pos = (float*)alloc(szf);
    float* x_neg = (float*)alloc(szf);
    _Float16* ksum_p = (_Float16*)alloc(szh);
    _Float16* ksum_n = merged ? (_Float16*)alloc(szh) : ksum_p;
    _Float16* hs_pa = (_Float16*)alloc(szh);
    _Float16* hs_pb = (_Float16*)alloc(szh);
    _Float16* hs_na = merged ? (_Float16*)alloc(szh) : hs_pa;
    _Float16* hs_nb = merged ? (_Float16*)alloc(szh) : hs_pb;
    float* dinv3 = (float*)alloc((size_t)(3 * N) * 4);
    int* cnt3 = (int*)alloc((size_t)(3 * N) * 4);
    int* cur3 = (int*)alloc((size_t)(3 * N) * 4);
    int* offs3 = (int*)alloc((3 * (size_t)N + 1) * 4);
    int* csr3 = (int*)alloc((size_t)Etot * 4);
    int* bsums = (int*)alloc(SCAN_T * 4);

    size_t used = (size_t)(p - (char*)d_ws);
    if (used > ws_size) used = ws_size;

    // R5: blanket zero of every used ws byte — deterministic initial state on
    // every call/replay (harness poisons ws with 0xAA). Keep this.
    hipMemsetAsync(d_ws, 0, used, stream);

    float* dinv_all = dinv3, * dinv_pos = dinv3 + N, * dinv_neg = dinv3 + 2 * N;
    const int* offs_all = offs3, * offs_pos = offs3 + N, * offs_neg = offs3 + 2 * N;

    dim3 blk(TPB);
    auto gblk = [](int n) { return dim3((n + TPB - 1) / TPB); };
    dim3 grid_rows((N + 7) / 8);
    const int nb64 = (N + 63) / 64;
    const int n3 = 3 * N;
    const int nbs = (n3 + SCAN_T - 1) / SCAN_T;
    // XCD-split grid: groups of 8 blocks; 4 pos + 4 neg per group.
    const int nsplit = ((nb64 + 3) / 4) * 8;

    // ---- fused CSR build (R5 path) ----
    SegG s0 = { Apos_src, Apos_dst, E1, 0 };
    SegG s1 = { Aneg_src, Aneg_dst, E2, 0 };
    SegG s2 = { dApos_src, dApos_dst, DE1, N };
    SegG s3 = { dAneg_src, dAneg_dst, DE2, 2 * N };
    count4<<<gblk(Etot), blk, 0, stream>>>(s0, s1, s2, s3, cnt3);
    dinv_from_cnt<<<gblk(n3), blk, 0, stream>>>(cnt3, dinv3, n3);
    scan_block<<<nbs, SCAN_T, 0, stream>>>(cnt3, n3, offs3, bsums);
    scan_sums<<<1, SCAN_T, 0, stream>>>(bsums, nbs);
    scan_add<<<gblk(n3), blk, 0, stream>>>(offs3, bsums, n3, Etot);
    {
        FSeg f0 = { Apos_src, Apos_dst, E1, offs3, cur3 };
        FSeg f1 = { Aneg_src, Aneg_dst, E2, offs3, cur3 };
        FSeg f2 = { dApos_src, dApos_dst, DE1, offs3 + N, cur3 + N };
        FSeg f3 = { dAneg_src, dAneg_dst, DE2, offs3 + 2 * N, cur3 + 2 * N };
        fill4<<<gblk(Etot), blk, 0, stream>>>(f0, f1, f2, f3, csr3);
    }

    auto mkjob = [&](const int* offs, const _Float16* hs_in, _Float16* hs_out,
                     const float* dinv, const float* dinv_next, const float* bias,
                     const float* wt, _Float16* ksum, float* x, const float* W) {
        Job j; j.offs = offs; j.csr = csr3; j.hs_in = hs_in; j.hs_out = hs_out;
        j.dinv = dinv; j.dinv_next = dinv_next; j.bias = bias; j.wt = wt;
        j.ksum = ksum; j.x = x; j.W = W; return j;
    };

    // ---- init GCN: H0 = relu(gcn(H_t)) -> x_pos, x_neg; epilogue seeds pos hs ----
    mm128_kernel<<<grid_rows, blk, 0, stream>>>(H_t, W_init, dinv_all, hs_pa, N);
    {
        Job j0 = mkjob(offs_all, hs_pa, hs_pb, dinv_all, dinv_pos, b_init,
                       nullptr, nullptr, x_pos, W_pos);
        agg_stage<<<nb64, blk, 0, stream>>>(j0, j0, nb64, 0.0f, 0, 1, 0, x_neg, N);
    }

    if (merged) {
        mm32_kernel<<<grid_rows, blk, 0, stream>>>(x_neg, W_neg, dinv_neg, hs_nb, N);
        for (int s = 0; s < 10; ++s) {
            float t0 = 0.1f * (float)s;
            int last_mm = (s == 9) ? 0 : 1;
            Job p1 = mkjob(offs_pos, hs_pb, hs_pa, dinv_pos, dinv_pos, b_pos, wt_pos, ksum_p, x_pos, W_pos);
            Job n1 = mkjob(offs_neg, hs_nb, hs_na, dinv_neg, dinv_neg, b_neg, wt_neg, ksum_n, x_neg, W_neg);
            agg_stage<<<nsplit, blk, 0, stream>>>(p1, n1, nb64, t0, 1, 1, 1, nullptr, N);
            Job p2 = p1; p2.hs_in = hs_pa; p2.hs_out = hs_pb;
            Job n2 = n1; n2.hs_in = hs_na; n2.hs_out = hs_nb;
            agg_stage<<<nsplit, blk, 0, stream>>>(p2, n2, nb64, t0 + 0.05f, 2, 1, 1, nullptr, N);
            agg_stage<<<nsplit, blk, 0, stream>>>(p1, n1, nb64, t0 + 0.05f, 3, 1, 1, nullptr, N);
            agg_stage<<<nsplit, blk, 0, stream>>>(p2, n2, nb64, t0 + 0.1f, 4, last_mm, 1, nullptr, N);
        }
    } else {
        for (int ode = 0; ode < 2; ++ode) {
            float* x = ode ? x_neg : x_pos;
            const float* W = ode ? W_neg : W_pos;
            const float* b = ode ? b_neg : b_pos;
            const float* wt = ode ? wt_neg : wt_pos;
            const float* dinv = ode ? dinv_neg : dinv_pos;
            const int* offs = ode ? offs_neg : offs_pos;
            if (ode == 1) {
                mm32_kernel<<<grid_rows, blk, 0, stream>>>(x, W, dinv, hs_pb, N);
            }
            for (int s = 0; s < 10; ++s) {
                float t0 = 0.1f * (float)s;
                int last_mm = (s == 9) ? 0 : 1;
                Job j1 = mkjob(offs, hs_pb, hs_pa, dinv, dinv, b, wt, ksum_p, x, W);
                Job j2 = j1; j2.hs_in = hs_pa; j2.hs_out = hs_pb;
                agg_stage<<<nb64, blk, 0, stream>>>(j1, j1, nb64, t0, 1, 1, 0, nullptr, N);
                agg_stage<<<nb64, blk, 0, stream>>>(j2, j2, nb64, t0 + 0.05f, 2, 1, 0, nullptr, N);
                agg_stage<<<nb64, blk, 0, stream>>>(j1, j1, nb64, t0 + 0.05f, 3, 1, 0, nullptr, N);
                agg_stage<<<nb64, blk, 0, stream>>>(j2, j2, nb64, t0 + 0.1f, 4, last_mm, 0, nullptr, N);
            }
        }
    }

    // ---- combine + layernorm ----
    combine_kernel<<<grid_rows, blk, 0, stream>>>(x_pos, x_neg, W_comb, b_comb, ln_g, ln_b,
                                                  (float*)d_out, N);
}

// Round 10
// 2060.897 us; speedup vs baseline: 1.4504x; 1.0404x over previous
//
#include <hip/hip_runtime.h>
#include <math.h>

// DynamiSE: GCN + 2x RK4 neural ODE + combine/LN.
// R1: CSR gather, coef folded into matmul (hs = dinv * x@W).
// R2: mm32 fused into agg epilogue, hs double-buffered.
// R3: merged pos/neg dispatch.
// R4: fp16 hs (64B gather rows). FAILED replay (read-before-write of poison).
// R5: blanket memset(0) of used ws every call (determinism insurance; keep!).
// R6: radix CSR build REGRESSED (bucket windows thrash all 8 L2s) -> reverted.
// R7: persistent kernel REGRESSED (gather is fabric-fetch-bound) -> reverted.
// R9: XCD-split + fp16 ksum: small gain; gather fabric replication is structural.
// R10: rank-based atomic-free CSR fill (rank recorded in count pass; dedicated
//      rank buffer, NO aliasing; cursor-fill fallback if ws too small).

#define TPB 256
#define SCAN_T 1024

typedef _Float16 h8 __attribute__((ext_vector_type(8)));
typedef float f8 __attribute__((ext_vector_type(8)));

// ---------- CSR build ----------

struct SegG { const int* src; const int* dst; int n; int goff; };
struct FSeg { const int* src; const int* dst; int n; const int* offs; int* cur; };

// count (+ optional rank recording, indexed by fused edge position)
__global__ void count4(SegG s0, SegG s1, SegG s2, SegG s3, int* __restrict__ cnt3,
                       int* __restrict__ rank) {
    int i = blockIdx.x * blockDim.x + threadIdx.x;
    SegG s; int e;
    if (i < s0.n) { s = s0; e = i; }
    else if (i < s0.n + s1.n) { s = s1; e = i - s0.n; }
    else if (i < s0.n + s1.n + s2.n) { s = s2; e = i - s0.n - s1.n; }
    else if (i < s0.n + s1.n + s2.n + s3.n) { s = s3; e = i - s0.n - s1.n - s2.n; }
    else return;
    int r = atomicAdd(&cnt3[s.goff + s.dst[e]], 1);
    if (rank) rank[i] = r;
}

// atomic-free fill using recorded ranks
__global__ void fill4_rank(SegG s0, SegG s1, SegG s2, SegG s3,
                           const int* __restrict__ offs3, const int* __restrict__ rank,
                           int* __restrict__ csr) {
    int i = blockIdx.x * blockDim.x + threadIdx.x;
    SegG s; int e;
    if (i < s0.n) { s = s0; e = i; }
    else if (i < s0.n + s1.n) { s = s1; e = i - s0.n; }
    else if (i < s0.n + s1.n + s2.n) { s = s2; e = i - s0.n - s1.n; }
    else if (i < s0.n + s1.n + s2.n + s3.n) { s = s3; e = i - s0.n - s1.n - s2.n; }
    else return;
    csr[offs3[s.goff + s.dst[e]] + rank[i]] = s.src[e];
}

// fallback cursor fill (R5-proven)
__global__ void fill4(FSeg s0, FSeg s1, FSeg s2, FSeg s3, int* __restrict__ csr) {
    int i = blockIdx.x * blockDim.x + threadIdx.x;
    FSeg s; int e;
    if (i < s0.n) { s = s0; e = i; }
    else if (i < s0.n + s1.n) { s = s1; e = i - s0.n; }
    else if (i < s0.n + s1.n + s2.n) { s = s2; e = i - s0.n - s1.n; }
    else if (i < s0.n + s1.n + s2.n + s3.n) { s = s3; e = i - s0.n - s1.n - s2.n; }
    else return;
    int d = s.dst[e];
    int pos = s.offs[d] + atomicAdd(&s.cur[d], 1);
    csr[pos] = s.src[e];
}

__global__ void dinv_from_cnt(const int* __restrict__ cnt, float* __restrict__ dinv, int n) {
    int i = blockIdx.x * blockDim.x + threadIdx.x;
    if (i < n) dinv[i] = rsqrtf(1.0f + (float)cnt[i]);
}

__global__ void scan_block(const int* __restrict__ in, int n, int* __restrict__ out,
                           int* __restrict__ bsums) {
    __shared__ int sh[SCAN_T];
    int tx = threadIdx.x;
    int g = blockIdx.x * SCAN_T + tx;
    int v = (g < n) ? in[g] : 0;
    sh[tx] = v;
    __syncthreads();
    for (int off = 1; off < SCAN_T; off <<= 1) {
        int t = (tx >= off) ? sh[tx - off] : 0;
        __syncthreads();
        sh[tx] += t;
        __syncthreads();
    }
    if (g < n) out[g] = sh[tx] - v;
    if (tx == SCAN_T - 1) bsums[blockIdx.x] = sh[tx];
}

__global__ void scan_sums(int* __restrict__ bsums, int nb) {
    __shared__ int sh[SCAN_T];
    int tx = threadIdx.x;
    int v = (tx < nb) ? bsums[tx] : 0;
    sh[tx] = v;
    __syncthreads();
    for (int off = 1; off < SCAN_T; off <<= 1) {
        int t = (tx >= off) ? sh[tx - off] : 0;
        __syncthreads();
        sh[tx] += t;
        __syncthreads();
    }
    if (tx < nb) bsums[tx] = sh[tx] - v;
}

__global__ void scan_add(int* __restrict__ offs, const int* __restrict__ bsums, int n, int total) {
    int g = blockIdx.x * blockDim.x + threadIdx.x;
    if (g < n) offs[g] += bsums[g >> 10];
    if (g == 0) offs[n] = total;
}

// ---------- seed matmuls: hs16 = fp16(dinv * (x @ W)) ----------

__global__ void mm32_kernel(const float* __restrict__ x, const float* __restrict__ W,
                            const float* __restrict__ dinv, _Float16* __restrict__ hs, int N) {
    __shared__ float Ws[32][32];
    __shared__ float xs[8][32];
    int tid = threadIdx.x;
    for (int i = tid; i < 32 * 32; i += TPB) Ws[i >> 5][i & 31] = W[i];
    int base = blockIdx.x * 8;
    {
        int idx = base * 32 + tid;
        xs[tid >> 5][tid & 31] = (idx < N * 32) ? x[idx] : 0.0f;
    }
    __syncthreads();
    int row = tid >> 5, c = tid & 31;
    int gr = base + row;
    float acc = 0.0f;
#pragma unroll
    for (int k = 0; k < 32; ++k) acc += xs[row][k] * Ws[k][c];
    if (gr < N) hs[gr * 32 + c] = (_Float16)(acc * dinv[gr]);
}

__global__ void mm128_kernel(const float* __restrict__ x, const float* __restrict__ W,
                             const float* __restrict__ dinv, _Float16* __restrict__ hs, int N) {
    __shared__ float Ws[128][32];
    __shared__ float xs[8][128];
    int tid = threadIdx.x;
    for (int i = tid; i < 128 * 32; i += TPB) Ws[i >> 5][i & 31] = W[i];
    int base = blockIdx.x * 8;
    for (int i = tid; i < 8 * 128; i += TPB) {
        int idx = base * 128 + i;
        xs[i >> 7][i & 127] = (idx < N * 128) ? x[idx] : 0.0f;
    }
    __syncthreads();
    int row = tid >> 5, c = tid & 31;
    int gr = base + row;
    float acc = 0.0f;
#pragma unroll
    for (int k = 0; k < 128; ++k) acc += xs[row][k] * Ws[k][c];
    if (gr < N) hs[gr * 32 + c] = (_Float16)(acc * dinv[gr]);
}

// ---------- fused CSR aggregate + RK4 stage + next matmul ----------

struct Job {
    const int* offs; const int* csr;
    const _Float16* hs_in; _Float16* hs_out;
    const float* dinv; const float* dinv_next;
    const float* bias; const float* wt;
    _Float16* ksum; float* x;
    const float* W;
};

// 4 lanes/node (8 channels each), 64 nodes/block.
// split=0: blocks [0,nbg) -> jp, rest -> jn.
// split=1: XCD-aware: blockIdx%8 < 4 -> jp else jn.
__global__ __launch_bounds__(TPB) void agg_stage(Job jp, Job jn, int nbg, float t,
                                                 int stage, int do_mm, int split,
                                                 float* __restrict__ x2, int N) {
    __shared__ float Ws[32][32];
    __shared__ float xts[64][36];
    __shared__ int soffs[65];

    bool isP; int bid;
    if (split) {
        int xcd = blockIdx.x & 7;
        isP = xcd < 4;
        bid = ((int)blockIdx.x >> 3) * 4 + (xcd & 3);
        if (bid >= nbg) return;
    } else {
        isP = (int)blockIdx.x < nbg;
        bid = isP ? blockIdx.x : (blockIdx.x - nbg);
    }
    const Job& J = isP ? jp : jn;
    int nbase = bid * 64;
    int tid = threadIdx.x;
    int lnode = tid >> 2, q = tid & 3;
    int node = nbase + lnode;
    bool valid = node < N;

    if (do_mm) {
        for (int i = tid; i < 32 * 32; i += TPB) Ws[i >> 5][i & 31] = J.W[i];
    }
    if (tid < 65) {
        int ix = nbase + tid; if (ix > N) ix = N;
        soffs[tid] = J.offs[ix];
    }
    __syncthreads();

    f8 xrow;
#pragma unroll
    for (int j = 0; j < 8; ++j) xrow[j] = 0.f;

    if (valid) {
        const h8* hsv = (const h8*)J.hs_in;
        const int* __restrict__ csr = J.csr;
        int r0 = soffs[lnode], r1 = soffs[lnode + 1];
        f8 acc = __builtin_convertvector(hsv[node * 4 + q], f8); // self-loop
        int i = r0;
        for (; i + 4 <= r1; i += 4) {
            int s0 = csr[i], s1 = csr[i + 1], s2 = csr[i + 2], s3 = csr[i + 3];
            h8 v0 = hsv[s0 * 4 + q];
            h8 v1 = hsv[s1 * 4 + q];
            h8 v2 = hsv[s2 * 4 + q];
            h8 v3 = hsv[s3 * 4 + q];
            acc += (__builtin_convertvector(v0, f8) + __builtin_convertvector(v1, f8))
                 + (__builtin_convertvector(v2, f8) + __builtin_convertvector(v3, f8));
        }
        for (; i < r1; ++i)
            acc += __builtin_convertvector(hsv[csr[i] * 4 + q], f8);

        float dv = J.dinv[node];
        f8 bb = ((const f8*)J.bias)[q];
        f8 kv;
#pragma unroll
        for (int j = 0; j < 8; ++j) kv[j] = fmaxf(acc[j] * dv + bb[j], 0.f);
        if (J.wt) {
            f8 w = ((const f8*)J.wt)[q];
#pragma unroll
            for (int j = 0; j < 8; ++j) kv[j] *= 1.f / (1.f + expf(-t * w[j]));
        }
        int idx = node * 4 + q;
        f8* x8 = (f8*)J.x;
        h8* ks8 = (h8*)J.ksum;
        if (stage == 0) {
            x8[idx] = kv;
            ((f8*)x2)[idx] = kv;
            xrow = kv;
        } else if (stage == 4) {
            f8 ks = __builtin_convertvector(ks8[idx], f8);
            f8 xv = x8[idx];
            const float cc = 0.1f / 6.0f;
#pragma unroll
            for (int j = 0; j < 8; ++j) xv[j] += cc * (ks[j] + kv[j]);
            x8[idx] = xv;
            xrow = xv;
        } else {
            float a = (stage == 3) ? 0.1f : 0.05f;
            f8 xv = x8[idx];
#pragma unroll
            for (int j = 0; j < 8; ++j) xrow[j] = xv[j] + a * kv[j];
            if (stage == 1) {
                ks8[idx] = __builtin_convertvector(kv, h8);
            } else {
                f8 ks = __builtin_convertvector(ks8[idx], f8);
#pragma unroll
                for (int j = 0; j < 8; ++j) ks[j] += 2.f * kv[j];
                ks8[idx] = __builtin_convertvector(ks, h8);
            }
        }
    }

    if (do_mm) {
        if (valid) {
#pragma unroll
            for (int j = 0; j < 8; ++j) xts[lnode][q * 8 + j] = xrow[j];
        }
        __syncthreads();
        if (valid) {
            f8 accm;
#pragma unroll
            for (int j = 0; j < 8; ++j) accm[j] = 0.f;
#pragma unroll
            for (int k = 0; k < 32; ++k) {
                float xv = xts[lnode][k];
                f8 w = *(const f8*)&Ws[k][q * 8];
                accm += xv * w;
            }
            accm *= J.dinv_next[node];
            ((h8*)J.hs_out)[node * 4 + q] = __builtin_convertvector(accm, h8);
        }
    }
}

// ---------- combine + layernorm ----------

__global__ void combine_kernel(const float* __restrict__ zp, const float* __restrict__ zn,
                               const float* __restrict__ Wc, const float* __restrict__ bc,
                               const float* __restrict__ g, const float* __restrict__ be,
                               float* __restrict__ out, int N) {
    __shared__ float Ws[64][32];
    __shared__ float zs[8][64];
    int tid = threadIdx.x;
    for (int i = tid; i < 64 * 32; i += TPB) Ws[i >> 5][i & 31] = Wc[i];
    int base = blockIdx.x * 8;
    {
        int r = tid >> 5, c = tid & 31;
        int gr = base + r;
        zs[r][c] = (gr < N) ? zp[gr * 32 + c] : 0.0f;
        zs[r][32 + c] = (gr < N) ? zn[gr * 32 + c] : 0.0f;
    }
    __syncthreads();
    int row = tid >> 5, c = tid & 31;
    int gr = base + row;
    float acc = bc[c];
#pragma unroll
    for (int k = 0; k < 64; ++k) acc += zs[row][k] * Ws[k][c];
    float s = acc, sq = acc * acc;
#pragma unroll
    for (int off = 16; off; off >>= 1) {
        s += __shfl_xor(s, off, 32);
        sq += __shfl_xor(sq, off, 32);
    }
    float mu = s * (1.0f / 32.0f);
    float var = sq * (1.0f / 32.0f) - mu * mu;
    float y = (acc - mu) * rsqrtf(var + 1e-5f) * g[c] + be[c];
    if (gr < N) out[gr * 32 + c] = y;
}

// ---------- host orchestration ----------

extern "C" void kernel_launch(void* const* d_in, const int* in_sizes, int n_in,
                              void* d_out, int out_size, void* d_ws, size_t ws_size,
                              hipStream_t stream) {
    const float* H_t = (const float*)d_in[0];
    const int* Apos = (const int*)d_in[1];
    const int* Aneg = (const int*)d_in[2];
    const int* dApos = (const int*)d_in[3];
    const int* dAneg = (const int*)d_in[4];
    const float* W_init = (const float*)d_in[5];
    const float* b_init = (const float*)d_in[6];
    const float* W_pos = (const float*)d_in[7];
    const float* b_pos = (const float*)d_in[8];
    const float* wt_pos = (const float*)d_in[9];
    const float* W_neg = (const float*)d_in[10];
    const float* b_neg = (const float*)d_in[11];
    const float* wt_neg = (const float*)d_in[12];
    const float* W_comb = (const float*)d_in[13];
    const float* b_comb = (const float*)d_in[14];
    const float* ln_g = (const float*)d_in[15];
    const float* ln_b = (const float*)d_in[16];

    const int N = in_sizes[0] / 128;
    const int E1 = in_sizes[1] / 2;
    const int E2 = in_sizes[2] / 2;
    const int DE1 = in_sizes[3] / 2;
    const int DE2 = in_sizes[4] / 2;
    const int Etot = E1 + E2 + DE1 + DE2;

    const int* Apos_src = Apos, * Apos_dst = Apos + E1;
    const int* Aneg_src = Aneg, * Aneg_dst = Aneg + E2;
    const int* dApos_src = dApos, * dApos_dst = dApos + DE1;
    const int* dAneg_src = dAneg, * dAneg_dst = dAneg + DE2;

    const size_t n32 = (size_t)N * 32;
    const size_t szf = n32 * 4;
    const size_t szh = n32 * 2;
    auto al = [](size_t b) { return (b + 255) & ~(size_t)255; };

    size_t small_bytes = 3 * al((size_t)(3 * N) * 4)   /* dinv3, cnt3, cur3 */
                       + al((3 * (size_t)N + 1) * 4)   /* offs3 */
                       + al((size_t)Etot * 4)          /* csr3 */
                       + al(SCAN_T * 4);
    size_t need_merged = 2 * al(szf) + 6 * al(szh) + small_bytes;
    size_t need_rank = need_merged + al((size_t)Etot * 4);
    bool merged = ws_size >= need_merged + 4096;
    bool use_rank = ws_size >= need_rank + 4096;

    char* p = (char*)d_ws;
    auto alloc = [&](size_t bytes) -> void* {
        void* r = (void*)p;
        p += al(bytes);
        return r;
    };
    float* x_pos = (float*)alloc(szf);
    float* x_neg = (float*)alloc(szf);
    _Float16* ksum_p = (_Float16*)alloc(szh);
    _Float16* ksum_n = merged ? (_Float16*)alloc(szh) : ksum_p;
    _Float16* hs_pa = (_Float16*)alloc(szh);
    _Float16* hs_pb = (_Float16*)alloc(szh);
    _Float16* hs_na = merged ? (_Float16*)alloc(szh) : hs_pa;
    _Float16* hs_nb = merged ? (_Float16*)alloc(szh) : hs_pb;
    float* dinv3 = (float*)alloc((size_t)(3 * N) * 4);
    int* cnt3 = (int*)alloc((size_t)(3 * N) * 4);
    int* cur3 = (int*)alloc((size_t)(3 * N) * 4);
    int* offs3 = (int*)alloc((3 * (size_t)N + 1) * 4);
    int* csr3 = (int*)alloc((size_t)Etot * 4);
    int* bsums = (int*)alloc(SCAN_T * 4);
    int* rank = use_rank ? (int*)alloc((size_t)Etot * 4) : nullptr;

    size_t used = (size_t)(p - (char*)d_ws);
    if (used > ws_size) used = ws_size;

    // R5: blanket zero of every used ws byte — deterministic initial state on
    // every call/replay (harness poisons ws with 0xAA). Keep this.
    hipMemsetAsync(d_ws, 0, used, stream);

    float* dinv_all = dinv3, * dinv_pos = dinv3 + N, * dinv_neg = dinv3 + 2 * N;
    const int* offs_all = offs3, * offs_pos = offs3 + N, * offs_neg = offs3 + 2 * N;

    dim3 blk(TPB);
    auto gblk = [](int n) { return dim3((n + TPB - 1) / TPB); };
    dim3 grid_rows((N + 7) / 8);
    const int nb64 = (N + 63) / 64;
    const int n3 = 3 * N;
    const int nbs = (n3 + SCAN_T - 1) / SCAN_T;
    const int nsplit = ((nb64 + 3) / 4) * 8;

    // ---- fused CSR build ----
    SegG s0 = { Apos_src, Apos_dst, E1, 0 };
    SegG s1 = { Aneg_src, Aneg_dst, E2, 0 };
    SegG s2 = { dApos_src, dApos_dst, DE1, N };
    SegG s3 = { dAneg_src, dAneg_dst, DE2, 2 * N };
    count4<<<gblk(Etot), blk, 0, stream>>>(s0, s1, s2, s3, cnt3, rank);
    dinv_from_cnt<<<gblk(n3), blk, 0, stream>>>(cnt3, dinv3, n3);
    scan_block<<<nbs, SCAN_T, 0, stream>>>(cnt3, n3, offs3, bsums);
    scan_sums<<<1, SCAN_T, 0, stream>>>(bsums, nbs);
    scan_add<<<gblk(n3), blk, 0, stream>>>(offs3, bsums, n3, Etot);
    if (use_rank) {
        fill4_rank<<<gblk(Etot), blk, 0, stream>>>(s0, s1, s2, s3, offs3, rank, csr3);
    } else {
        FSeg f0 = { Apos_src, Apos_dst, E1, offs3, cur3 };
        FSeg f1 = { Aneg_src, Aneg_dst, E2, offs3, cur3 };
        FSeg f2 = { dApos_src, dApos_dst, DE1, offs3 + N, cur3 + N };
        FSeg f3 = { dAneg_src, dAneg_dst, DE2, offs3 + 2 * N, cur3 + 2 * N };
        fill4<<<gblk(Etot), blk, 0, stream>>>(f0, f1, f2, f3, csr3);
    }

    auto mkjob = [&](const int* offs, const _Float16* hs_in, _Float16* hs_out,
                     const float* dinv, const float* dinv_next, const float* bias,
                     const float* wt, _Float16* ksum, float* x, const float* W) {
        Job j; j.offs = offs; j.csr = csr3; j.hs_in = hs_in; j.hs_out = hs_out;
        j.dinv = dinv; j.dinv_next = dinv_next; j.bias = bias; j.wt = wt;
        j.ksum = ksum; j.x = x; j.W = W; return j;
    };

    // ---- init GCN: H0 = relu(gcn(H_t)) -> x_pos, x_neg; epilogue seeds pos hs ----
    mm128_kernel<<<grid_rows, blk, 0, stream>>>(H_t, W_init, dinv_all, hs_pa, N);
    {
        Job j0 = mkjob(offs_all, hs_pa, hs_pb, dinv_all, dinv_pos, b_init,
                       nullptr, nullptr, x_pos, W_pos);
        agg_stage<<<nb64, blk, 0, stream>>>(j0, j0, nb64, 0.0f, 0, 1, 0, x_neg, N);
    }

    if (merged) {
        mm32_kernel<<<grid_rows, blk, 0, stream>>>(x_neg, W_neg, dinv_neg, hs_nb, N);
        for (int s = 0; s < 10; ++s) {
            float t0 = 0.1f * (float)s;
            int last_mm = (s == 9) ? 0 : 1;
            Job p1 = mkjob(offs_pos, hs_pb, hs_pa, dinv_pos, dinv_pos, b_pos, wt_pos, ksum_p, x_pos, W_pos);
            Job n1 = mkjob(offs_neg, hs_nb, hs_na, dinv_neg, dinv_neg, b_neg, wt_neg, ksum_n, x_neg, W_neg);
            agg_stage<<<nsplit, blk, 0, stream>>>(p1, n1, nb64, t0, 1, 1, 1, nullptr, N);
            Job p2 = p1; p2.hs_in = hs_pa; p2.hs_out = hs_pb;
            Job n2 = n1; n2.hs_in = hs_na; n2.hs_out = hs_nb;
            agg_stage<<<nsplit, blk, 0, stream>>>(p2, n2, nb64, t0 + 0.05f, 2, 1, 1, nullptr, N);
            agg_stage<<<nsplit, blk, 0, stream>>>(p1, n1, nb64, t0 + 0.05f, 3, 1, 1, nullptr, N);
            agg_stage<<<nsplit, blk, 0, stream>>>(p2, n2, nb64, t0 + 0.1f, 4, last_mm, 1, nullptr, N);
        }
    } else {
        for (int ode = 0; ode < 2; ++ode) {
            float* x = ode ? x_neg : x_pos;
            const float* W = ode ? W_neg : W_pos;
            const float* b = ode ? b_neg : b_pos;
            const float* wt = ode ? wt_neg : wt_pos;
            const float* dinv = ode ? dinv_neg : dinv_pos;
            const int* offs = ode ? offs_neg : offs_pos;
            if (ode == 1) {
                mm32_kernel<<<grid_rows, blk, 0, stream>>>(x, W, dinv, hs_pb, N);
            }
            for (int s = 0; s < 10; ++s) {
                float t0 = 0.1f * (float)s;
                int last_mm = (s == 9) ? 0 : 1;
                Job j1 = mkjob(offs, hs_pb, hs_pa, dinv, dinv, b, wt, ksum_p, x, W);
                Job j2 = j1; j2.hs_in = hs_pa; j2.hs_out = hs_pb;
                agg_stage<<<nb64, blk, 0, stream>>>(j1, j1, nb64, t0, 1, 1, 0, nullptr, N);
                agg_stage<<<nb64, blk, 0, stream>>>(j2, j2, nb64, t0 + 0.05f, 2, 1, 0, nullptr, N);
                agg_stage<<<nb64, blk, 0, stream>>>(j1, j1, nb64, t0 + 0.05f, 3, 1, 0, nullptr, N);
                agg_stage<<<nb64, blk, 0, stream>>>(j2, j2, nb64, t0 + 0.1f, 4, last_mm, 0, nullptr, N);
            }
        }
    }

    // ---- combine + layernorm ----
    combine_kernel<<<grid_rows, blk, 0, stream>>>(x_pos, x_neg, W_comb, b_comb, ln_g, ln_b,
                                                  (float*)d_out, N);
}